// Round 4
// baseline (257.729 us; speedup 1.0000x reference)
//
#include <hip/hip_runtime.h>

#define D 64
#define N_GRAPHS 128
#define D_OUT 16
#define BCAP 16384   // max edges per 256-node bucket (avg 6400, sigma ~80)
#define TILE 4096    // edges per bin_kernel block

typedef unsigned short u16;
typedef unsigned int u32;
typedef unsigned char u8;
typedef __attribute__((ext_vector_type(8))) short bf16x8;
typedef __attribute__((ext_vector_type(4))) float f32x4;
typedef __attribute__((ext_vector_type(2))) float f32x2;

__device__ inline u16 f2bf(float f) {  // round-to-nearest-even
  u32 u = __float_as_uint(f);
  return (u16)((u + 0x7fffu + ((u >> 16) & 1u)) >> 16);
}
__device__ inline float bf2f(u16 b) { return __uint_as_float((u32)b << 16); }
__device__ inline f32x2 bfpair(u32 v) {  // packed bf16 pair -> 2 fp32 (exact)
  return (f32x2){__uint_as_float(v << 16), __uint_as_float(v & 0xffff0000u)};
}

// ===========================================================================
// x (fp32) -> bf16, 4 elems/thread. Side duties (spare blocks):
//   block 0:     init CSR cursors; cvec = b_rel3@Wlin + b_lin
//   blocks 1-8:  M1 = Wrel3@Wlin, M2 = Wroot3@Wlin (layer-3 folded into pool)
//   blocks 9-16: Wrel1/Wroot1/Wrel2/Wroot2 -> bf16 TRANSPOSED (WbT[o][k])
//                for MFMA B-fragments in the fused layer kernels.
// ===========================================================================
__global__ __launch_bounds__(256) void cvt_bf16_kernel(
    const float* __restrict__ in, u16* __restrict__ out, int n4,
    int* __restrict__ cursors, int nbuck,
    const float* __restrict__ Wrel1, const float* __restrict__ Wroot1,
    const float* __restrict__ Wrel2, const float* __restrict__ Wroot2,
    const float* __restrict__ Wrel3, const float* __restrict__ Wroot3,
    const float* __restrict__ Wlin, const float* __restrict__ brel3,
    const float* __restrict__ blin,
    float* __restrict__ M1, float* __restrict__ M2, float* __restrict__ cvec,
    u16* __restrict__ WbT1r, u16* __restrict__ WbT1o,
    u16* __restrict__ WbT2r, u16* __restrict__ WbT2o) {
  int t = threadIdx.x;
  if (blockIdx.x == 0) {
    if (t < nbuck) cursors[t] = t * BCAP;
    if (t >= 240) {
      int o = t - 240;
      float c = blin[o];
#pragma unroll
      for (int j = 0; j < D; j++) c = fmaf(brel3[j], Wlin[j * D_OUT + o], c);
      cvec[o] = c;
    }
  } else if (blockIdx.x <= 8) {
    int idx = (blockIdx.x - 1) * 256 + t;      // 0..2047
    const float* W = (idx < 1024) ? Wrel3 : Wroot3;
    float* M = (idx < 1024) ? M1 : M2;
    int id = idx & 1023;
    int k = id >> 4, o = id & 15;
    float acc = 0.0f;
#pragma unroll
    for (int j = 0; j < D; j++) acc = fmaf(W[k * D + j], Wlin[j * D_OUT + o], acc);
    M[id] = acc;
  } else if (blockIdx.x <= 16) {
    int tid = (blockIdx.x - 9) * 256 + t;      // 0..2047; 512 threads per matrix
    int mat = tid >> 9;
    int r = tid & 511;
    int o = r >> 3;            // output column 0..63
    int k0 = (r & 7) * 8;      // k-chunk of 8
    const float* Wsrc = (mat == 0) ? Wrel1 : (mat == 1) ? Wroot1
                       : (mat == 2) ? Wrel2 : Wroot2;
    u16* Wdst = (mat == 0) ? WbT1r : (mat == 1) ? WbT1o
               : (mat == 2) ? WbT2r : WbT2o;
    u16 tmp[8];
#pragma unroll
    for (int j = 0; j < 8; j++) tmp[j] = f2bf(Wsrc[(k0 + j) * D + o]);
    uint4 pw;
    pw.x = (u32)tmp[0] | ((u32)tmp[1] << 16);
    pw.y = (u32)tmp[2] | ((u32)tmp[3] << 16);
    pw.z = (u32)tmp[4] | ((u32)tmp[5] << 16);
    pw.w = (u32)tmp[6] | ((u32)tmp[7] << 16);
    *(uint4*)&Wdst[o * D + k0] = pw;
  }
  int i = blockIdx.x * 256 + t;
  if (i >= n4) return;
  float4 v = ((const float4*)in)[i];
  ushort4 o4;
  o4.x = f2bf(v.x); o4.y = f2bf(v.y); o4.z = f2bf(v.z); o4.w = f2bf(v.w);
  ((ushort4*)out)[i] = o4;
}

// ===========================================================================
// CSR build: LDS counting sort (scattered work in LDS, contiguous HBM writes).
// Pass 1: bin edges by dst>>8.
// ===========================================================================
__global__ __launch_bounds__(256) void bin_kernel(
    const int* __restrict__ src, const int* __restrict__ dst,
    int* __restrict__ cursors, u32* __restrict__ binned,
    int n_edges, int nbuck) {
  __shared__ u32 ent[TILE];
  __shared__ u8 ebk[TILE];
  __shared__ int hist[256];
  __shared__ int startb[256];
  __shared__ int cur[256];
  __shared__ int gbase[256];
  int t = threadIdx.x;
  hist[t] = 0;
  __syncthreads();

  int base = blockIdx.x * TILE;
  int cnt = n_edges - base;
  if (cnt > TILE) cnt = TILE;

  int mys[16], myd[16];
#pragma unroll
  for (int j = 0; j < 16; j++) {
    int i = base + t + j * 256;
    if (t + j * 256 < cnt) {
      mys[j] = src[i];
      myd[j] = dst[i];
      atomicAdd(&hist[myd[j] >> 8], 1);
    } else {
      myd[j] = -1;
    }
  }
  __syncthreads();
  int myc = hist[t];  // this thread's bucket count (bucket id == t)
  for (int off = 1; off < 256; off <<= 1) {
    int tmp = (t >= off) ? hist[t - off] : 0;
    __syncthreads();
    hist[t] += tmp;
    __syncthreads();
  }
  int excl = hist[t] - myc;
  startb[t] = excl;
  cur[t] = excl;
  __syncthreads();

#pragma unroll
  for (int j = 0; j < 16; j++) {
    if (myd[j] >= 0) {
      int b = myd[j] >> 8;
      int p = atomicAdd(&cur[b], 1);
      ent[p] = ((u32)myd[j] << 16) | (u32)mys[j];
      ebk[p] = (u8)b;
    }
  }
  __syncthreads();

  if (t < nbuck && myc > 0) gbase[t] = atomicAdd(&cursors[t], myc);
  __syncthreads();

#pragma unroll
  for (int j = 0; j < 16; j++) {
    int p = t + j * 256;
    if (p < cnt) {
      int b = ebk[p];
      int gpos = gbase[b] + (p - startb[b]);
      if (gpos < (b + 1) * BCAP) binned[gpos] = ent[p];
    }
  }
}

// Pass 2: one block per bucket. Computes its own edge-base prefix (scan
// folded in), builds the CSR segment in LDS, writes coalesced.
__global__ __launch_bounds__(256) void csr_kernel(
    const u32* __restrict__ binned, const int* __restrict__ cursors,
    u16* __restrict__ csr_src, int* __restrict__ offsets,
    int n_nodes, int nbuck) {
  __shared__ int deg[256];
  __shared__ int cur[256];
  __shared__ int red[256];
  __shared__ u16 lcsr[BCAP];
  int b = blockIdx.x, t = threadIdx.x;
  int cnt = cursors[b] - b * BCAP;
  if (cnt < 0) cnt = 0;
  if (cnt > BCAP) cnt = BCAP;

  // ebase = sum of counts of buckets < b (256-wide reduction, b < 256)
  int c = 0;
  if (t < b) {
    c = cursors[t] - t * BCAP;
    if (c < 0) c = 0;
    if (c > BCAP) c = BCAP;
  }
  red[t] = c;
  __syncthreads();
  for (int off = 128; off > 0; off >>= 1) {
    if (t < off) red[t] += red[t + off];
    __syncthreads();
  }
  int ebase = red[0];

  int nodeBase = b << 8;
  int nn = n_nodes - nodeBase;
  if (nn > 256) nn = 256;

  deg[t] = 0;
  __syncthreads();
  const u32* be = binned + (size_t)b * BCAP;
  for (int i = t; i < cnt; i += 256)
    atomicAdd(&deg[(be[i] >> 16) - nodeBase], 1);
  __syncthreads();
  int myd = deg[t];
  for (int off = 1; off < 256; off <<= 1) {
    int tmp = (t >= off) ? deg[t - off] : 0;
    __syncthreads();
    deg[t] += tmp;
    __syncthreads();
  }
  int loff = deg[t] - myd;  // exclusive
  cur[t] = loff;
  if (t < nn) offsets[nodeBase + t] = ebase + loff;
  if (b == nbuck - 1 && t == 0) offsets[n_nodes] = ebase + cnt;
  __syncthreads();

  for (int i = t; i < cnt; i += 256) {
    u32 e = be[i];
    int ln = (e >> 16) - nodeBase;
    int p = atomicAdd(&cur[ln], 1);
    lcsr[p] = (u16)(e & 0xffffu);
  }
  __syncthreads();
  for (int i = t; i < cnt; i += 256) csr_src[ebase + i] = lcsr[i];
}

#define ACC8(a, r) \
  a[0] += bfpair(r.x); a[1] += bfpair(r.y); a[2] += bfpair(r.z); a[3] += bfpair(r.w);

// Degree-balance prologue: rank the block's 32 nodes by degree (descending);
// wave w's 8 subgroups take ranks [w*8, w*8+8) -> near-equal trip counts
// within each wave, cutting the max-of-8 divergence waste (~20%).
#define BALANCE_PROLOGUE(soff, permAr, blockBase, n_nodes, offsets)     \
  {                                                                     \
    int t_ = threadIdx.x;                                               \
    if (t_ < 33) {                                                      \
      int idx = blockBase + t_;                                         \
      if (idx > n_nodes) idx = n_nodes;                                 \
      soff[t_] = offsets[idx];                                          \
    }                                                                   \
    __syncthreads();                                                    \
    if (t_ < 32) {                                                      \
      int d_ = (blockBase + t_ < n_nodes) ? soff[t_ + 1] - soff[t_] : -1; \
      int r_ = 0;                                                       \
      for (int j_ = 0; j_ < 32; j_++) {                                 \
        int dj_ = (blockBase + j_ < n_nodes) ? soff[j_ + 1] - soff[j_] : -1; \
        if (dj_ > d_ || (dj_ == d_ && j_ < t_)) r_++;                   \
      }                                                                 \
      permAr[r_] = (u8)t_;                                              \
    }                                                                   \
    __syncthreads();                                                    \
  }

// ===========================================================================
// Fused layer (layers 1,2): degree-balanced gather (subgroup-per-node,
// 32 nodes/block) -> LDS bf16 -> 4 waves x 8 mfma_f32_16x16x32_bf16 ->
// bias/relu -> h_out (bf16).
//   A-frag: lane l holds A[l&15][(l>>4)*8+j]  (16B contiguous ds_read)
//   B-frag: lane l holds B[(l>>4)*8+j][l&15] = WbT[l&15-col][k..] contiguous
//   D-frag: col=lane&15, row=(lane>>4)*4+reg  [m89-verified]
// ===========================================================================
__global__ __launch_bounds__(256) void fused_layer_kernel(
    const u16* __restrict__ h, const int* __restrict__ offsets,
    const u16* __restrict__ csr_src,
    const u16* __restrict__ WbTrel, const u16* __restrict__ WbTroot,
    const float* __restrict__ brel,
    u16* __restrict__ h_out, int n_nodes, int do_relu) {
  __shared__ __align__(16) u16 ldsA[32 * 72];  // agg rows, bf16, pad 8
  __shared__ __align__(16) u16 ldsX[32 * 72];  // own rows, bf16, pad 8
  __shared__ int soff[33];
  __shared__ u8 permAr[32];
  int w = threadIdx.x >> 6;
  int lane = threadIdx.x & 63;
  int sub = lane >> 3;          // node slot within wave
  int fo = (lane & 7) * 8;      // feature offset (bf16 elems)
  int blockBase = blockIdx.x * 32;

  BALANCE_PROLOGUE(soff, permAr, blockBase, n_nodes, offsets)

  int ln = permAr[w * 8 + sub];       // local node this subgroup gathers
  int node = blockBase + ln;
  bool valid = node < n_nodes;
  int start = soff[ln];
  int end = soff[ln + 1];
  if (!valid) end = start;
  int lrow = ln * 72;

  // own row (root-term input) -> ldsX
  uint4 xr = make_uint4(0, 0, 0, 0);
  if (valid) xr = *(const uint4*)(h + ((size_t)node << 6) + fo);
  *(uint4*)&ldsX[lrow + fo] = xr;

  // gather neighbors
  f32x2 a0[4] = {{0,0},{0,0},{0,0},{0,0}};
  f32x2 a1[4] = {{0,0},{0,0},{0,0},{0,0}};
  int i = start;
  for (; i + 3 < end; i += 4) {
    int s0 = csr_src[i], s1 = csr_src[i + 1], s2 = csr_src[i + 2], s3 = csr_src[i + 3];
    uint4 r0 = *(const uint4*)(h + ((size_t)s0 << 6) + fo);
    uint4 r1 = *(const uint4*)(h + ((size_t)s1 << 6) + fo);
    uint4 r2 = *(const uint4*)(h + ((size_t)s2 << 6) + fo);
    uint4 r3 = *(const uint4*)(h + ((size_t)s3 << 6) + fo);
    ACC8(a0, r0) ACC8(a1, r1) ACC8(a0, r2) ACC8(a1, r3)
  }
  for (; i < end; i++) {
    int s0 = csr_src[i];
    uint4 r0 = *(const uint4*)(h + ((size_t)s0 << 6) + fo);
    ACC8(a0, r0)
  }
#pragma unroll
  for (int k = 0; k < 4; k++) a0[k] += a1[k];

  uint4 pa;
  pa.x = (u32)f2bf(a0[0].x) | ((u32)f2bf(a0[0].y) << 16);
  pa.y = (u32)f2bf(a0[1].x) | ((u32)f2bf(a0[1].y) << 16);
  pa.z = (u32)f2bf(a0[2].x) | ((u32)f2bf(a0[2].y) << 16);
  pa.w = (u32)f2bf(a0[3].x) | ((u32)f2bf(a0[3].y) << 16);
  *(uint4*)&ldsA[lrow + fo] = pa;
  __syncthreads();

  // ---- MFMA dense phase: OUT[32x64] = A@Wrel + X@Wroot + b ----
  int mt = w & 1;               // m-tile (16 nodes)
  int ntb = (w >> 1) * 2;       // first n-tile of this wave's pair
  int lr = lane & 15, lk = lane >> 4;
  int arow = (mt * 16 + lr) * 72;
  bf16x8 af0 = *(const bf16x8*)&ldsA[arow + lk * 8];        // kstep 0
  bf16x8 af1 = *(const bf16x8*)&ldsA[arow + 32 + lk * 8];   // kstep 1
  bf16x8 xf0 = *(const bf16x8*)&ldsX[arow + lk * 8];
  bf16x8 xf1 = *(const bf16x8*)&ldsX[arow + 32 + lk * 8];
#pragma unroll
  for (int tt = 0; tt < 2; tt++) {
    int nt = ntb + tt;
    int wrow = (nt * 16 + lr) * D + lk * 8;
    bf16x8 br0 = *(const bf16x8*)(WbTrel + wrow);
    bf16x8 br1 = *(const bf16x8*)(WbTrel + wrow + 32);
    bf16x8 bo0 = *(const bf16x8*)(WbTroot + wrow);
    bf16x8 bo1 = *(const bf16x8*)(WbTroot + wrow + 32);
    f32x4 acc = {0.0f, 0.0f, 0.0f, 0.0f};
    acc = __builtin_amdgcn_mfma_f32_16x16x32_bf16(af0, br0, acc, 0, 0, 0);
    acc = __builtin_amdgcn_mfma_f32_16x16x32_bf16(af1, br1, acc, 0, 0, 0);
    acc = __builtin_amdgcn_mfma_f32_16x16x32_bf16(xf0, bo0, acc, 0, 0, 0);
    acc = __builtin_amdgcn_mfma_f32_16x16x32_bf16(xf1, bo1, acc, 0, 0, 0);
    float bias = brel[nt * 16 + lr];
#pragma unroll
    for (int r = 0; r < 4; r++) {
      int onode = blockBase + mt * 16 + lk * 4 + r;
      if (onode < n_nodes) {
        float v = acc[r] + bias;
        if (do_relu) v = fmaxf(v, 0.0f);
        h_out[((size_t)onode << 6) + nt * 16 + lr] = f2bf(v);
      }
    }
  }
}

// ===========================================================================
// Gather (layer 3, no dense): degree-balanced subgroup-per-node, agg fp32.
// ===========================================================================
__global__ __launch_bounds__(256) void gather_kernel(
    const u16* __restrict__ h, const int* __restrict__ offsets,
    const u16* __restrict__ csr_src, float* __restrict__ agg, int n_nodes) {
  __shared__ int soff[33];
  __shared__ u8 permAr[32];
  int w = threadIdx.x >> 6;
  int lane = threadIdx.x & 63;
  int sub = lane >> 3;
  int fo = (lane & 7) * 8;
  int blockBase = blockIdx.x * 32;

  BALANCE_PROLOGUE(soff, permAr, blockBase, n_nodes, offsets)

  int ln = permAr[w * 8 + sub];
  int node = blockBase + ln;
  bool valid = node < n_nodes;
  int start = soff[ln];
  int end = soff[ln + 1];
  if (!valid) end = start;

  f32x2 a0[4] = {{0,0},{0,0},{0,0},{0,0}};
  f32x2 a1[4] = {{0,0},{0,0},{0,0},{0,0}};
  int i = start;
  for (; i + 3 < end; i += 4) {
    int s0 = csr_src[i], s1 = csr_src[i + 1], s2 = csr_src[i + 2], s3 = csr_src[i + 3];
    uint4 r0 = *(const uint4*)(h + ((size_t)s0 << 6) + fo);
    uint4 r1 = *(const uint4*)(h + ((size_t)s1 << 6) + fo);
    uint4 r2 = *(const uint4*)(h + ((size_t)s2 << 6) + fo);
    uint4 r3 = *(const uint4*)(h + ((size_t)s3 << 6) + fo);
    ACC8(a0, r0) ACC8(a1, r1) ACC8(a0, r2) ACC8(a1, r3)
  }
  for (; i < end; i++) {
    int s0 = csr_src[i];
    uint4 r0 = *(const uint4*)(h + ((size_t)s0 << 6) + fo);
    ACC8(a0, r0)
  }
#pragma unroll
  for (int k = 0; k < 4; k++) a0[k] += a1[k];
  if (valid) {
    float* ap = agg + ((size_t)node << 6) + fo;
    *(float4*)(ap)     = make_float4(a0[0].x, a0[0].y, a0[1].x, a0[1].y);
    *(float4*)(ap + 4) = make_float4(a0[2].x, a0[2].y, a0[3].x, a0[3].y);
  }
}

// ===========================================================================
// Pool agg3 (fp32) + h2 (bf16) AND apply the folded layer-3+final linear in
// the same block (final2 kernel absorbed). One block per graph.
// ===========================================================================
__global__ __launch_bounds__(256) void pool_final_kernel(
    const float* __restrict__ aggA, const u16* __restrict__ hH,
    const int* __restrict__ batch,
    const float* __restrict__ M1, const float* __restrict__ M2,
    const float* __restrict__ cvec, const float* __restrict__ blin,
    float* __restrict__ out, int n_nodes) {
  __shared__ int seg[2];
  __shared__ float redA[256], redH[256];
  __shared__ float mA[64], mH[64];
  int g = blockIdx.x;
  int t = threadIdx.x;
  if (t < 2) {
    int target = g + t;
    int lo = 0, hi = n_nodes;
    while (lo < hi) {
      int mid = (lo + hi) >> 1;
      if (batch[mid] < target) lo = mid + 1; else hi = mid;
    }
    seg[t] = lo;
  }
  __syncthreads();
  int start = seg[0], end = seg[1];
  int f = t & 63, sub = t >> 6;
  float aA = 0.0f, aH = 0.0f;
  for (int n = start + sub; n < end; n += 4) {
    aA += aggA[((size_t)n << 6) + f];
    aH += bf2f(hH[((size_t)n << 6) + f]);
  }
  redA[t] = aA;
  redH[t] = aH;
  __syncthreads();
  if (sub == 0) {
    float inv = (end > start) ? 1.0f / (float)(end - start) : 0.0f;
    mA[f] = (redA[f] + redA[64 + f] + redA[128 + f] + redA[192 + f]) * inv;
    mH[f] = (redH[f] + redH[64 + f] + redH[128 + f] + redH[192 + f]) * inv;
  }
  __syncthreads();
  if (t < 16) {
    float acc;
    if (end > start) {
      acc = cvec[t];
#pragma unroll
      for (int k = 0; k < D; k++)
        acc = fmaf(mA[k], M1[k * D_OUT + t], fmaf(mH[k], M2[k * D_OUT + t], acc));
    } else {
      acc = blin[t];
    }
    out[g * D_OUT + t] = acc;
  }
}

extern "C" void kernel_launch(void* const* d_in, const int* in_sizes, int n_in,
                              void* d_out, int out_size, void* d_ws, size_t ws_size,
                              hipStream_t stream) {
  const float* x     = (const float*)d_in[0];
  const int*   ei    = (const int*)d_in[1];
  const int*   batch = (const int*)d_in[3];
  const float* Wrel1 = (const float*)d_in[4];
  const float* brel1 = (const float*)d_in[5];
  const float* Wroot1= (const float*)d_in[6];
  const float* Wrel2 = (const float*)d_in[7];
  const float* brel2 = (const float*)d_in[8];
  const float* Wroot2= (const float*)d_in[9];
  const float* Wrel3 = (const float*)d_in[10];
  const float* brel3 = (const float*)d_in[11];
  const float* Wroot3= (const float*)d_in[12];
  const float* Wlin  = (const float*)d_in[13];
  const float* blin  = (const float*)d_in[14];
  float* out = (float*)d_out;

  const int n_edges = in_sizes[1] / 2;
  const int n_nodes = in_sizes[0] / D;
  const int* src = ei;
  const int* dst = ei + n_edges;
  const int nbuck = (n_nodes + 255) >> 8;  // 196

  // ---- workspace carve-up (binned and agg alias: binned dead after csr) ----
  char* p = (char*)d_ws;
  size_t binned_bytes = (size_t)nbuck * BCAP * sizeof(u32);        // ~12.85MB
  size_t agg_bytes = (size_t)n_nodes * D * sizeof(float);          // 12.8MB
  u32* binned  = (u32*)p;
  float* agg   = (float*)p;
  p += (binned_bytes > agg_bytes ? binned_bytes : agg_bytes);
  float* M1     = (float*)p; p += (size_t)D * D_OUT * sizeof(float);
  float* M2     = (float*)p; p += (size_t)D * D_OUT * sizeof(float);
  float* cvec   = (float*)p; p += 16 * sizeof(float);
  int* cursors  = (int*)p;   p += 256 * sizeof(int);
  int* offsets  = (int*)p;   p += (size_t)(n_nodes + 4) * sizeof(int);
  u16* hX       = (u16*)p;   p += (size_t)n_nodes * D * sizeof(u16);
  u16* h1       = (u16*)p;   p += (size_t)n_nodes * D * sizeof(u16);
  u16* h2       = (u16*)p;   p += (size_t)n_nodes * D * sizeof(u16);
  u16* csr_src  = (u16*)p;   p += (size_t)n_edges * sizeof(u16);
  u16* WbT1r    = (u16*)p;   p += (size_t)D * D * sizeof(u16);
  u16* WbT1o    = (u16*)p;   p += (size_t)D * D * sizeof(u16);
  u16* WbT2r    = (u16*)p;   p += (size_t)D * D * sizeof(u16);
  u16* WbT2o    = (u16*)p;   p += (size_t)D * D * sizeof(u16);

  const int bin_blocks = (n_edges + TILE - 1) / TILE;
  const int fused_blocks = (n_nodes + 31) / 32;  // 32 nodes/block
  const int cvt_n4 = n_nodes * D / 4;

  // ---- CSR build + x->bf16 (+cursors, M1/M2/cvec, W->bf16^T precompute) ----
  cvt_bf16_kernel<<<(cvt_n4 + 255) / 256, 256, 0, stream>>>(
      x, hX, cvt_n4, cursors, nbuck, Wrel1, Wroot1, Wrel2, Wroot2,
      Wrel3, Wroot3, Wlin, brel3, blin, M1, M2, cvec,
      WbT1r, WbT1o, WbT2r, WbT2o);
  bin_kernel<<<bin_blocks, 256, 0, stream>>>(src, dst, cursors, binned, n_edges, nbuck);
  csr_kernel<<<nbuck, 256, 0, stream>>>(binned, cursors, csr_src, offsets, n_nodes, nbuck);

  // ---- layers 1,2: fused gather + MFMA dense ----
  fused_layer_kernel<<<fused_blocks, 256, 0, stream>>>(
      hX, offsets, csr_src, WbT1r, WbT1o, brel1, h1, n_nodes, 1);
  fused_layer_kernel<<<fused_blocks, 256, 0, stream>>>(
      h1, offsets, csr_src, WbT2r, WbT2o, brel2, h2, n_nodes, 1);

  // ---- layer 3 gather only (dense3 folded into pooled side) ----
  gather_kernel<<<fused_blocks, 256, 0, stream>>>(h2, offsets, csr_src, agg, n_nodes);

  // ---- pool agg3 + h2 and apply folded final linear ----
  pool_final_kernel<<<N_GRAPHS, 256, 0, stream>>>(
      agg, h2, batch, M1, M2, cvec, blin, out, n_nodes);
}